// Round 13
// baseline (297.143 us; speedup 1.0000x reference)
//
#include <hip/hip_runtime.h>
#include <math.h>

#define NN 100000      // nodes
#define CD 32          // classes / hidden
#define NPB 4          // waves per block in gather kernels (2 nodes per wave)

#define B1N ((NN + 255) >> 8)   // 391 coarse buckets (256 nodes each)
#define EPB_A 2048              // edges per partition block (256 thr x 8)

// R26 POST-MORTEM (do not retry): cooperative mega-kernel with grid.sync()
// ran 1485 us — grid.sync at ~1500 blocks costs ~100+ us/sync on gfx950.
// R24 (feature-blocked 3-pass gather): 3x latency rounds/node. NO.
// R25 (4 nodes/wave): neutral vs 2. Keep 2.
// R28: gathers were under-vectorized (4 B/lane). dwordx4 row reads cut
// VMEM wave-instructions per 16-edge node 9->3 (g50) / 5->2 (g32); line
// transactions unchanged, so worst-case neutral, issue-bound case ~1.5x.

typedef unsigned int   uint32;
typedef unsigned short ushort16;

// fp32 -> bf16 round-to-nearest-even
__device__ __forceinline__ ushort16 f2b(float f) {
    uint32 u = __float_as_uint(f);
    u = (u + 0x7FFFu + ((u >> 16) & 1u)) >> 16;
    return (ushort16)u;
}
// packed bf16 pair -> two fp32 (exact)
__device__ __forceinline__ float b2f_lo(uint32 u) { return __uint_as_float(u << 16); }
__device__ __forceinline__ float b2f_hi(uint32 u) { return __uint_as_float(u & 0xFFFF0000u); }

// ---------------------------------------------------------------------------
// R22: order-preserving bf16->u16 key space (max-of-keys == key-of-max);
// per-uint gather max = ONE v_pk_max_u16.
__device__ __forceinline__ uint32 pkmax(uint32 a, uint32 b) {
    uint32 d;
    asm("v_pk_max_u16 %0, %1, %2" : "=v"(d) : "v"(a), "v"(b));
    return d;
}
// fp32 -> bf16 key (scalar)
__device__ __forceinline__ uint32 key16(float f) {
    uint32 b = (uint32)f2b(f);
    return b ^ ((__float_as_uint(f) >> 31) ? 0xFFFFu : 0x8000u);
}
// packed key pair -> packed bf16 pair (general sign)
__device__ __forceinline__ uint32 dec_pk(uint32 k) {
    uint32 m = (~k >> 15) & 0x00010001u;            // 1 where original < 0
    uint32 X = 0x80008000u | ((m << 15) - m);       // per half: neg?0xFFFF:0x8000
    return k ^ X;
}

// Inline is64 detection (R17).
__device__ __forceinline__ int edge_is64(const void* edge) {
    const long long* p = (const long long*)edge;
    int lane = threadIdx.x & 63;
    int bad = 0;
    for (int i = lane; i < 512; i += 64) {
        long long v = p[i];
        if (v < 0 || v >= NN) bad = 1;
    }
    unsigned long long anybad = __ballot(bad);
    return (anybad == 0ULL) ? 1 : 0;
}

__device__ __forceinline__ int load_idx(const void* edge, int i, int is64) {
    if (is64) return (int)((const long long*)edge)[i];
    return ((const int*)edge)[i];
}

// ---------------------------------------------------------------------------
// Fused cvt + hist (R22). Monolithic stride-32 xb (128-B aligned rows).
__global__ __launch_bounds__(256) void cvt_hist_kernel(const float* __restrict__ x,
                                                       uint32* __restrict__ xb,
                                                       const void* edge, int E,
                                                       int* __restrict__ hist,
                                                       int nblkA) {
    __shared__ int lh[B1N];
    const int t = threadIdx.x;
    if ((int)blockIdx.x < nblkA) {
        const int is64 = edge_is64(edge);
        for (int b = t; b < B1N; b += 256) lh[b] = 0;
        __syncthreads();
        const int e0 = blockIdx.x * EPB_A + t;
#pragma unroll
        for (int k = 0; k < 8; ++k) {
            int e = e0 + k * 256;
            if (e < E) {
                int d = load_idx(edge, E + e, is64);
                atomicAdd(&lh[d >> 8], 1);
            }
        }
        __syncthreads();
        int* gh = hist + (size_t)blockIdx.x * B1N;
        for (int b = t; b < B1N; b += 256) gh[b] = lh[b];
    } else {
        const int tt = (blockIdx.x - nblkA) * 256 + t;
        if (tt >= NN * 32) return;
        const int n = tt >> 5;
        const int c = tt & 31;
        if (c >= 25) { xb[tt] = 0; return; }
        float2 v = *(const float2*)&x[n * 50 + 2 * c];
        xb[tt] = key16(v.x) | (key16(v.y) << 16);
    }
}

// One block per bin: exclusive scan of hist[b][bin] over blocks b (in place),
// bin total to binTotal[bin]. Supports nblk <= 1024 (4 per thread).
__global__ __launch_bounds__(256) void scanA_kernel(int* __restrict__ hist,
                                                    int nblk,
                                                    int* __restrict__ binTotal) {
    __shared__ int ts[256];
    const int bin = blockIdx.x;
    const int t = threadIdx.x;
    const int base = t * 4;
    int v0 = (base + 0 < nblk) ? hist[(size_t)(base + 0) * B1N + bin] : 0;
    int v1 = (base + 1 < nblk) ? hist[(size_t)(base + 1) * B1N + bin] : 0;
    int v2 = (base + 2 < nblk) ? hist[(size_t)(base + 2) * B1N + bin] : 0;
    int v3 = (base + 3 < nblk) ? hist[(size_t)(base + 3) * B1N + bin] : 0;
    const int s = v0 + v1 + v2 + v3;
    ts[t] = s;
    __syncthreads();
    for (int off = 1; off < 256; off <<= 1) {
        int u = (t >= off) ? ts[t - off] : 0;
        __syncthreads();
        ts[t] += u;
        __syncthreads();
    }
    int e = ts[t] - s;
    if (base + 0 < nblk) { hist[(size_t)(base + 0) * B1N + bin] = e; e += v0; }
    if (base + 1 < nblk) { hist[(size_t)(base + 1) * B1N + bin] = e; e += v1; }
    if (base + 2 < nblk) { hist[(size_t)(base + 2) * B1N + bin] = e; e += v2; }
    if (base + 3 < nblk) { hist[(size_t)(base + 3) * B1N + bin] = e; e += v3; }
    if (t == 255) binTotal[bin] = ts[255];
}

// In-block exclusive scan of binTotal[B1N] -> lbase[B1N+1] (LDS).
__device__ __forceinline__ void scan_bins_lds(const int* __restrict__ binTotal,
                                              int* ts, int* lbase) {
    const int t = threadIdx.x;
    const int base = t * 2;
    const int v0 = (base + 0 < B1N) ? binTotal[base + 0] : 0;
    const int v1 = (base + 1 < B1N) ? binTotal[base + 1] : 0;
    const int s = v0 + v1;
    ts[t] = s;
    __syncthreads();
    for (int off = 1; off < 256; off <<= 1) {
        int u = (t >= off) ? ts[t - off] : 0;
        __syncthreads();
        ts[t] += u;
        __syncthreads();
    }
    const int e = ts[t] - s;
    if (base + 0 < B1N) lbase[base + 0] = e;
    if (base + 1 < B1N) lbase[base + 1] = e + v0;
    if (t == 255) lbase[B1N] = ts[255];     // == E
    __syncthreads();
}

__global__ __launch_bounds__(256) void scatter_kernel(const void* edge, int E,
                                                      const int* __restrict__ hist,
                                                      const int* __restrict__ binTotal,
                                                      uint32* __restrict__ bucketed) {
    __shared__ int ts[256];
    __shared__ int lbase[B1N + 1];
    __shared__ int cur[B1N];
    const int is64 = edge_is64(edge);
    const int t = threadIdx.x;
    scan_bins_lds(binTotal, ts, lbase);
    const int* gh = hist + (size_t)blockIdx.x * B1N;
    for (int b = t; b < B1N; b += 256) cur[b] = lbase[b] + gh[b];
    __syncthreads();
    const int e0 = blockIdx.x * EPB_A + t;
#pragma unroll
    for (int k = 0; k < 8; ++k) {
        int e = e0 + k * 256;
        if (e < E) {
            int s = load_idx(edge, e, is64);
            int d = load_idx(edge, E + e, is64);
            int pos = atomicAdd(&cur[d >> 8], 1);   // LDS atomic
            bucketed[pos] = (uint32)s | ((uint32)(d & 255) << 17);
        }
    }
}

__global__ __launch_bounds__(256) void bucket_kernel(const uint32* __restrict__ bucketed,
                                                     const int* __restrict__ binTotal,
                                                     int* __restrict__ offsets,
                                                     int* __restrict__ csr_src) {
    __shared__ int ts[256];
    __shared__ int lbase[B1N + 1];
    __shared__ int h[256];
    __shared__ int sc[256];
    __shared__ int cur[256];
    const int bkt = blockIdx.x;
    const int t = threadIdx.x;
    scan_bins_lds(binTotal, ts, lbase);
    const int start = lbase[bkt];
    const int end   = lbase[bkt + 1];
    h[t] = 0;
    __syncthreads();
    for (int i = start + t; i < end; i += 256)
        atomicAdd(&h[bucketed[i] >> 17], 1);        // LDS atomic
    __syncthreads();
    const int v = h[t];
    sc[t] = v;
    __syncthreads();
    for (int off = 1; off < 256; off <<= 1) {
        int u = (t >= off) ? sc[t - off] : 0;
        __syncthreads();
        sc[t] += u;
        __syncthreads();
    }
    const int excl = sc[t] - v;
    const int node = bkt * 256 + t;
    if (node < NN) offsets[node] = start + excl;    // coalesced
    cur[t] = start + excl;
    __syncthreads();
    for (int i = start + t; i < end; i += 256) {
        uint32 p = bucketed[i];
        int pos = atomicAdd(&cur[p >> 17], 1);      // LDS atomic
        csr_src[pos] = (int)(p & 0x1FFFFu);         // L2-local scatter (16KB window)
    }
    if (bkt == B1N - 1 && t == 0) offsets[NN] = end;   // == E
}

// ---------------------------------------------------------------------------
// Gather-max kernels, key space, dwordx4 rows (R28).
// gather50: 8 lanes cover a 128-B row (slot e = lane>>3, chunk c = lane&7,
// 16 B each) -> ONE wave instruction reads 8 edges' rows. Permuted index
// load csr_src[ib + 8c + e] keeps every shfl source inside the executing
// 8-lane slot-group (R21 invariant; edge k lives at lane (k&7)*8 + (k>>3)).
// gather32: 4 lanes cover a 64-B row (e = lane>>2, c = lane&3) -> one
// instruction reads 16 edges' rows; index myidx = 16c + e.
// R23 2-node pipelining kept: both index-window loads issue up front.

__device__ __forceinline__ void g50_window(uint32* a_, int sidx, int mm,
                                           const char* hbase, uint32 coff,
                                           int e, int lb) {
    int k = e;
    for (; k + 8 < mm; k += 16) {          // 2 loads (16 edges) in flight
        int s0 = __shfl(sidx, lb + (k >> 3));
        int s1 = __shfl(sidx, lb + ((k + 8) >> 3));
        uint4 u0 = *(const uint4*)(hbase + ((((uint32)s0) << 7) | coff));
        uint4 u1 = *(const uint4*)(hbase + ((((uint32)s1) << 7) | coff));
        a_[0] = pkmax(a_[0], u0.x); a_[1] = pkmax(a_[1], u0.y);
        a_[2] = pkmax(a_[2], u0.z); a_[3] = pkmax(a_[3], u0.w);
        a_[4] = pkmax(a_[4], u1.x); a_[5] = pkmax(a_[5], u1.y);
        a_[6] = pkmax(a_[6], u1.z); a_[7] = pkmax(a_[7], u1.w);
    }
    for (; k < mm; k += 8) {
        int s = __shfl(sidx, lb + (k >> 3));
        uint4 u = *(const uint4*)(hbase + ((((uint32)s) << 7) | coff));
        a_[0] = pkmax(a_[0], u.x); a_[1] = pkmax(a_[1], u.y);
        a_[2] = pkmax(a_[2], u.z); a_[3] = pkmax(a_[3], u.w);
    }
}

__global__ void gather50_kernel(const uint32* __restrict__ hb,
                                const int* __restrict__ offsets,
                                const int* __restrict__ csr_src,
                                uint32* __restrict__ aggB) {
    const int tid  = threadIdx.x;
    const int g    = tid >> 6;
    const int lane = tid & 63;
    const int e    = lane >> 3;        // edge slot 0..7
    const int c    = lane & 7;         // 16-B chunk 0..7
    const int n0   = (blockIdx.x * NPB + g) * 2;
    if (n0 >= NN) return;
    const int n1   = n0 + 1;
    const bool has1 = (n1 < NN);

    const int beg0 = offsets[n0];
    const int end0 = offsets[n0 + 1];
    const int beg1 = end0;                         // offsets[n1] == offsets[n0+1]
    const int end1 = has1 ? offsets[n1 + 1] : end0;
    const char* hbase = (const char*)hb;
    const uint32 coff = (uint32)(c << 4);
    const int lb = e << 3;             // this slot-group's lane base
    const int myidx = 8 * c + e;       // permuted window layout

    uint32 a_[8], b_[8];
#pragma unroll
    for (int k = 0; k < 8; ++k) { a_[k] = 0; b_[k] = 0; }

    // First windows of both nodes: issue BOTH index loads before any rows.
    const int d0 = end0 - beg0, d1 = end1 - beg1;
    const int mm0 = d0 < 64 ? d0 : 64;
    const int mm1 = d1 < 64 ? d1 : 64;
    int sidx0 = 0, sidx1 = 0;
    if (myidx < mm0) sidx0 = csr_src[beg0 + myidx];
    if (myidx < mm1) sidx1 = csr_src[beg1 + myidx];
    g50_window(a_, sidx0, mm0, hbase, coff, e, lb);
    g50_window(b_, sidx1, mm1, hbase, coff, e, lb);
    // Rare extra windows (degree > 64)
    for (int ib = beg0 + 64; ib < end0; ib += 64) {
        const int rem = end0 - ib;
        const int mm = rem < 64 ? rem : 64;
        int s = (myidx < mm) ? csr_src[ib + myidx] : 0;
        g50_window(a_, s, mm, hbase, coff, e, lb);
    }
    for (int ib = beg1 + 64; ib < end1; ib += 64) {
        const int rem = end1 - ib;
        const int mm = rem < 64 ? rem : 64;
        int s = (myidx < mm) ? csr_src[ib + myidx] : 0;
        g50_window(b_, s, mm, hbase, coff, e, lb);
    }

    // fold 2-deep accumulators, then reduce across slots (xor lane bits 3..5)
    uint32 r0 = pkmax(a_[0], a_[4]), r1 = pkmax(a_[1], a_[5]);
    uint32 r2 = pkmax(a_[2], a_[6]), r3 = pkmax(a_[3], a_[7]);
    uint32 q0 = pkmax(b_[0], b_[4]), q1 = pkmax(b_[1], b_[5]);
    uint32 q2 = pkmax(b_[2], b_[6]), q3 = pkmax(b_[3], b_[7]);
#pragma unroll
    for (int m = 8; m <= 32; m <<= 1) {
        r0 = pkmax(r0, (uint32)__shfl_xor((int)r0, m));
        r1 = pkmax(r1, (uint32)__shfl_xor((int)r1, m));
        r2 = pkmax(r2, (uint32)__shfl_xor((int)r2, m));
        r3 = pkmax(r3, (uint32)__shfl_xor((int)r3, m));
        q0 = pkmax(q0, (uint32)__shfl_xor((int)q0, m));
        q1 = pkmax(q1, (uint32)__shfl_xor((int)q1, m));
        q2 = pkmax(q2, (uint32)__shfl_xor((int)q2, m));
        q3 = pkmax(q3, (uint32)__shfl_xor((int)q3, m));
    }
    if (e == 0) {                      // lanes 0..7, one uint4 per 16-B chunk
        uint4 w0, w1;
        if (beg0 == end0) { w0.x = w0.y = w0.z = w0.w = 0x80008000u; }
        else { w0.x = r0; w0.y = r1; w0.z = r2; w0.w = r3; }
        *(uint4*)(aggB + (size_t)n0 * 32 + c * 4) = w0;
        if (has1) {
            if (beg1 == end1) { w1.x = w1.y = w1.z = w1.w = 0x80008000u; }
            else { w1.x = q0; w1.y = q1; w1.z = q2; w1.w = q3; }
            *(uint4*)(aggB + (size_t)n1 * 32 + c * 4) = w1;
        }
    }
}

__device__ __forceinline__ void g32_window(uint32* a_, int sidx, int mm,
                                           const char* hbase, uint32 coff,
                                           int e, int lb) {
    int k = e;
    for (; k + 16 < mm; k += 32) {         // 2 loads (32 edges) in flight
        int s0 = __shfl(sidx, lb + (k >> 4));
        int s1 = __shfl(sidx, lb + ((k + 16) >> 4));
        uint4 u0 = *(const uint4*)(hbase + ((((uint32)s0) << 6) | coff));
        uint4 u1 = *(const uint4*)(hbase + ((((uint32)s1) << 6) | coff));
        a_[0] = pkmax(a_[0], u0.x); a_[1] = pkmax(a_[1], u0.y);
        a_[2] = pkmax(a_[2], u0.z); a_[3] = pkmax(a_[3], u0.w);
        a_[4] = pkmax(a_[4], u1.x); a_[5] = pkmax(a_[5], u1.y);
        a_[6] = pkmax(a_[6], u1.z); a_[7] = pkmax(a_[7], u1.w);
    }
    for (; k < mm; k += 16) {
        int s = __shfl(sidx, lb + (k >> 4));
        uint4 u = *(const uint4*)(hbase + ((((uint32)s) << 6) | coff));
        a_[0] = pkmax(a_[0], u.x); a_[1] = pkmax(a_[1], u.y);
        a_[2] = pkmax(a_[2], u.z); a_[3] = pkmax(a_[3], u.w);
    }
}

__global__ void gather32_kernel(const uint32* __restrict__ hb,
                                const int* __restrict__ offsets,
                                const int* __restrict__ csr_src,
                                uint32* __restrict__ aggB) {
    const int tid  = threadIdx.x;
    const int g    = tid >> 6;
    const int lane = tid & 63;
    const int e    = lane >> 2;        // edge slot 0..15
    const int c    = lane & 3;         // 16-B chunk 0..3
    const int n0   = (blockIdx.x * NPB + g) * 2;
    if (n0 >= NN) return;
    const int n1   = n0 + 1;
    const bool has1 = (n1 < NN);

    const int beg0 = offsets[n0];
    const int end0 = offsets[n0 + 1];
    const int beg1 = end0;                         // offsets[n1] == offsets[n0+1]
    const int end1 = has1 ? offsets[n1 + 1] : end0;
    const char* hbase = (const char*)hb;
    const uint32 coff = (uint32)(c << 4);
    const int lb = e << 2;             // this slot-group's lane base
    const int myidx = 16 * c + e;      // permuted window layout

    uint32 a_[8], b_[8];
#pragma unroll
    for (int k = 0; k < 8; ++k) { a_[k] = 0; b_[k] = 0; }

    const int d0 = end0 - beg0, d1 = end1 - beg1;
    const int mm0 = d0 < 64 ? d0 : 64;
    const int mm1 = d1 < 64 ? d1 : 64;
    int sidx0 = 0, sidx1 = 0;
    if (myidx < mm0) sidx0 = csr_src[beg0 + myidx];
    if (myidx < mm1) sidx1 = csr_src[beg1 + myidx];
    g32_window(a_, sidx0, mm0, hbase, coff, e, lb);
    g32_window(b_, sidx1, mm1, hbase, coff, e, lb);
    for (int ib = beg0 + 64; ib < end0; ib += 64) {
        const int rem = end0 - ib;
        const int mm = rem < 64 ? rem : 64;
        int s = (myidx < mm) ? csr_src[ib + myidx] : 0;
        g32_window(a_, s, mm, hbase, coff, e, lb);
    }
    for (int ib = beg1 + 64; ib < end1; ib += 64) {
        const int rem = end1 - ib;
        const int mm = rem < 64 ? rem : 64;
        int s = (myidx < mm) ? csr_src[ib + myidx] : 0;
        g32_window(b_, s, mm, hbase, coff, e, lb);
    }

    // fold 2-deep accumulators, then reduce across slots (xor lane bits 2..5)
    uint32 r0 = pkmax(a_[0], a_[4]), r1 = pkmax(a_[1], a_[5]);
    uint32 r2 = pkmax(a_[2], a_[6]), r3 = pkmax(a_[3], a_[7]);
    uint32 q0 = pkmax(b_[0], b_[4]), q1 = pkmax(b_[1], b_[5]);
    uint32 q2 = pkmax(b_[2], b_[6]), q3 = pkmax(b_[3], b_[7]);
#pragma unroll
    for (int m = 4; m <= 32; m <<= 1) {
        r0 = pkmax(r0, (uint32)__shfl_xor((int)r0, m));
        r1 = pkmax(r1, (uint32)__shfl_xor((int)r1, m));
        r2 = pkmax(r2, (uint32)__shfl_xor((int)r2, m));
        r3 = pkmax(r3, (uint32)__shfl_xor((int)r3, m));
        q0 = pkmax(q0, (uint32)__shfl_xor((int)q0, m));
        q1 = pkmax(q1, (uint32)__shfl_xor((int)q1, m));
        q2 = pkmax(q2, (uint32)__shfl_xor((int)q2, m));
        q3 = pkmax(q3, (uint32)__shfl_xor((int)q3, m));
    }
    if (e == 0) {                      // lanes 0..3, one uint4 per 16-B chunk
        uint4 w0, w1;
        if (beg0 == end0) { w0.x = w0.y = w0.z = w0.w = 0x80008000u; }
        else { w0.x = r0; w0.y = r1; w0.z = r2; w0.w = r3; }
        *(uint4*)(aggB + (size_t)n0 * 16 + c * 4) = w0;
        if (has1) {
            if (beg1 == end1) { w1.x = w1.y = w1.z = w1.w = 0x80008000u; }
            else { w1.x = q0; w1.y = q1; w1.z = q2; w1.w = q3; }
            *(uint4*)(aggB + (size_t)n1 * 16 + c * 4) = w1;
        }
    }
}

// ---------------------------------------------------------------------------
// Dense kernel (R11-proven): one lane per node; 32 fp32 accumulators; wave-
// uniform weight addresses scalarize to s_load. Inputs key-encoded (dec_pk
// on load); MODE 0 stores relu output as keys (relu >= 0 -> OR 0x80008000);
// MODE 2 = log_softmax -> fp32.
template <int DIN, int ASTR, int HSTR, int OSTR, int MODE>
__global__ void dense_kernel(const uint32* __restrict__ aggB,
                             const uint32* __restrict__ hB,
                             const float* __restrict__ Wl,
                             const float* __restrict__ bl,
                             const float* __restrict__ Wr,
                             void* __restrict__ out_v) {
    const int n = blockIdx.x * blockDim.x + threadIdx.x;
    if (n >= NN) return;

    float acc[CD];
#pragma unroll
    for (int j = 0; j < CD; ++j) acc[j] = bl[j];

    {
        const uint32* row = aggB + (size_t)n * ASTR;
        for (int c = 0; c < DIN / 4; ++c) {
            uint2 u = *(const uint2*)&row[c * 2];
            u.x = dec_pk(u.x); u.y = dec_pk(u.y);
            float d0 = b2f_lo(u.x), d1 = b2f_hi(u.x);
            float d2 = b2f_lo(u.y), d3 = b2f_hi(u.y);
            const float* w = Wl + c * 4 * CD;
#pragma unroll
            for (int j = 0; j < CD; ++j)
                acc[j] += d0 * w[j] + d1 * w[CD + j] + d2 * w[2 * CD + j] + d3 * w[3 * CD + j];
        }
        if (DIN % 4) {
            uint32 u = dec_pk(row[(DIN / 4) * 2]);
            float d0 = b2f_lo(u), d1 = b2f_hi(u);
            const float* w = Wl + (DIN - 2) * CD;
#pragma unroll
            for (int j = 0; j < CD; ++j)
                acc[j] += d0 * w[j] + d1 * w[CD + j];
        }
    }
    {
        const uint32* row = hB + (size_t)n * HSTR;
        for (int c = 0; c < DIN / 4; ++c) {
            uint2 u = *(const uint2*)&row[c * 2];
            u.x = dec_pk(u.x); u.y = dec_pk(u.y);
            float d0 = b2f_lo(u.x), d1 = b2f_hi(u.x);
            float d2 = b2f_lo(u.y), d3 = b2f_hi(u.y);
            const float* w = Wr + c * 4 * CD;
#pragma unroll
            for (int j = 0; j < CD; ++j)
                acc[j] += d0 * w[j] + d1 * w[CD + j] + d2 * w[2 * CD + j] + d3 * w[3 * CD + j];
        }
        if (DIN % 4) {
            uint32 u = dec_pk(row[(DIN / 4) * 2]);
            float d0 = b2f_lo(u), d1 = b2f_hi(u);
            const float* w = Wr + (DIN - 2) * CD;
#pragma unroll
            for (int j = 0; j < CD; ++j)
                acc[j] += d0 * w[j] + d1 * w[CD + j];
        }
    }

    if (MODE == 0) {
        uint32* orow = (uint32*)out_v + (size_t)n * OSTR;
#pragma unroll
        for (int c = 0; c < CD / 2; ++c) {
            float a0 = fmaxf(acc[2 * c],     0.0f);
            float a1 = fmaxf(acc[2 * c + 1], 0.0f);
            // relu output >= 0 -> key encode is just setting the top bit
            orow[c] = ((uint32)f2b(a0) | ((uint32)f2b(a1) << 16)) | 0x80008000u;
        }
    } else {
        float m = acc[0];
#pragma unroll
        for (int j = 1; j < CD; ++j) m = fmaxf(m, acc[j]);
        float s = 0.0f;
#pragma unroll
        for (int j = 0; j < CD; ++j) s += expf(acc[j] - m);
        const float lse = m + logf(s);
        float* orow = (float*)out_v + (size_t)n * CD;
#pragma unroll
        for (int j = 0; j < CD; ++j) orow[j] = acc[j] - lse;
    }
}

// ---------------------------------------------------------------------------
extern "C" void kernel_launch(void* const* d_in, const int* in_sizes, int n_in,
                              void* d_out, int out_size, void* d_ws, size_t ws_size,
                              hipStream_t stream) {
    const float* x    = (const float*)d_in[0];
    const void*  edge = d_in[1];
    const float* Wl1 = (const float*)d_in[2];
    const float* bl1 = (const float*)d_in[3];
    const float* Wr1 = (const float*)d_in[4];
    const float* Wl2 = (const float*)d_in[5];
    const float* bl2 = (const float*)d_in[6];
    const float* Wr2 = (const float*)d_in[7];
    const float* Wl3 = (const float*)d_in[8];
    const float* bl3 = (const float*)d_in[9];
    const float* Wr3 = (const float*)d_in[10];

    const int E = in_sizes[1] / 2;

    // Workspace carve-up (256B aligned), ~26 MB. bucketed + hist live in
    // d_out (dead before agg1 is written there); h2b reuses xb (dead after
    // dense-L1); agg3 reuses h1b (dead after dense-L2).
    char* ws = (char*)d_ws;
    size_t off = 0;
    auto carve = [&](size_t bytes) {
        void* p = ws + off;
        off = (off + bytes + 255) & ~(size_t)255;
        return p;
    };
    int*    offsets   = (int*)   carve((size_t)(NN + 1) * 4);
    int*    binTotal  = (int*)   carve((size_t)B1N * 4);
    int*    csr_src   = (int*)   carve((size_t)E * 4);
    uint32* xb        = (uint32*)carve((size_t)NN * 32 * 4);  // 12.8 MB
    uint32* h1b       = (uint32*)carve((size_t)NN * 16 * 4);  // 6.4 MB
    (void)ws_size; (void)n_in; (void)out_size;

    uint32* bucketed = (uint32*)d_out;     // 6.4 MB, dead before agg1
    int*    hist     = (int*)((char*)d_out + (((size_t)E * 4 + 255) & ~(size_t)255));
    uint32* agg1 = (uint32*)d_out;         // L1 agg, stride 32 (12.8 MB = d_out)
    uint32* agg2 = (uint32*)d_out;         // L2 agg, stride 16
    uint32* h2b  = xb;                     // xb dead after dense-L1
    uint32* agg3 = h1b;                    // h1b dead after dense-L2

    // CSR build, LDS-atomic bucketing; cvt fused into the hist dispatch.
    const int nblkA = (E + EPB_A - 1) / EPB_A;     // 782 for E=1.6M
    const int cvtb  = (NN * 32 + 255) / 256;       // 12500
    cvt_hist_kernel<<<nblkA + cvtb, 256, 0, stream>>>(x, xb, edge, E, hist, nblkA);
    scanA_kernel<<<B1N, 256, 0, stream>>>(hist, nblkA, binTotal);
    scatter_kernel<<<nblkA, 256, 0, stream>>>(edge, E, hist, binTotal, bucketed);
    bucket_kernel<<<B1N, 256, 0, stream>>>(bucketed, binTotal, offsets, csr_src);

    const int gb = (NN + NPB * 2 - 1) / (NPB * 2);   // 2 nodes per wave
    const int db = (NN + 255) / 256;                 // lane per node

    // Layer 1: 50 -> 32, relu
    gather50_kernel<<<gb, 256, 0, stream>>>(xb, offsets, csr_src, agg1);
    dense_kernel<50, 32, 32, 16, 0><<<db, 256, 0, stream>>>(agg1, xb, Wl1, bl1, Wr1, h1b);
    // Layer 2: 32 -> 32, relu
    gather32_kernel<<<gb, 256, 0, stream>>>(h1b, offsets, csr_src, agg2);
    dense_kernel<32, 16, 16, 16, 0><<<db, 256, 0, stream>>>(agg2, h1b, Wl2, bl2, Wr2, h2b);
    // Layer 3: 32 -> 32, log_softmax -> fp32 d_out
    gather32_kernel<<<gb, 256, 0, stream>>>(h2b, offsets, csr_src, agg3);
    dense_kernel<32, 16, 16, 0, 2><<<db, 256, 0, stream>>>(agg3, h2b, Wl3, bl3, Wr3, d_out);
}

// Round 15
// 289.095 us; speedup vs baseline: 1.0278x; 1.0278x over previous
//
#include <hip/hip_runtime.h>
#include <math.h>

#define NN 100000      // nodes
#define CD 32          // classes / hidden
#define NPB 4          // waves per block in gather kernels (2 nodes per wave)

#define B1N ((NN + 255) >> 8)   // 391 coarse buckets (256 nodes each)
#define EPB_A 2048              // edges per partition block (256 thr x 8)

// FALSIFIED PATHS (do not retry):
// R24 feature-blocked 3-pass gather: 3x latency rounds/node (68 us). NO.
// R25 4 nodes/wave: neutral-to-negative vs 2. Keep 2.
// R26 cooperative mega-kernel: grid.sync ~100+ us/sync at ~1500 blocks
//     on gfx950 (1485 us total). Dispatch boundaries are far cheaper.
// R28 dwordx4 gather rows: 297 vs 288 — gathers are line-transaction/
//     latency bound, not VMEM-issue bound (1 line/row either way); wider
//     temporaries + deeper shfl reduce tree cost more than saved issue.
// (R14 submission of this exact source failed on infra: container died.)

typedef unsigned int   uint32;
typedef unsigned short ushort16;

// fp32 -> bf16 round-to-nearest-even
__device__ __forceinline__ ushort16 f2b(float f) {
    uint32 u = __float_as_uint(f);
    u = (u + 0x7FFFu + ((u >> 16) & 1u)) >> 16;
    return (ushort16)u;
}
// packed bf16 pair -> two fp32 (exact)
__device__ __forceinline__ float b2f_lo(uint32 u) { return __uint_as_float(u << 16); }
__device__ __forceinline__ float b2f_hi(uint32 u) { return __uint_as_float(u & 0xFFFF0000u); }

// ---------------------------------------------------------------------------
// R22: order-preserving bf16->u16 key space (max-of-keys == key-of-max);
// per-uint gather max = ONE v_pk_max_u16.
__device__ __forceinline__ uint32 pkmax(uint32 a, uint32 b) {
    uint32 d;
    asm("v_pk_max_u16 %0, %1, %2" : "=v"(d) : "v"(a), "v"(b));
    return d;
}
// fp32 -> bf16 key (scalar)
__device__ __forceinline__ uint32 key16(float f) {
    uint32 b = (uint32)f2b(f);
    return b ^ ((__float_as_uint(f) >> 31) ? 0xFFFFu : 0x8000u);
}
// packed key pair -> packed bf16 pair (general sign)
__device__ __forceinline__ uint32 dec_pk(uint32 k) {
    uint32 m = (~k >> 15) & 0x00010001u;            // 1 where original < 0
    uint32 X = 0x80008000u | ((m << 15) - m);       // per half: neg?0xFFFF:0x8000
    return k ^ X;
}

// Inline is64 detection (R17).
__device__ __forceinline__ int edge_is64(const void* edge) {
    const long long* p = (const long long*)edge;
    int lane = threadIdx.x & 63;
    int bad = 0;
    for (int i = lane; i < 512; i += 64) {
        long long v = p[i];
        if (v < 0 || v >= NN) bad = 1;
    }
    unsigned long long anybad = __ballot(bad);
    return (anybad == 0ULL) ? 1 : 0;
}

__device__ __forceinline__ int load_idx(const void* edge, int i, int is64) {
    if (is64) return (int)((const long long*)edge)[i];
    return ((const int*)edge)[i];
}

// ---------------------------------------------------------------------------
// Fused cvt + hist (R22). Monolithic stride-32 xb (128-B aligned rows).
__global__ __launch_bounds__(256) void cvt_hist_kernel(const float* __restrict__ x,
                                                       uint32* __restrict__ xb,
                                                       const void* edge, int E,
                                                       int* __restrict__ hist,
                                                       int nblkA) {
    __shared__ int lh[B1N];
    const int t = threadIdx.x;
    if ((int)blockIdx.x < nblkA) {
        const int is64 = edge_is64(edge);
        for (int b = t; b < B1N; b += 256) lh[b] = 0;
        __syncthreads();
        const int e0 = blockIdx.x * EPB_A + t;
#pragma unroll
        for (int k = 0; k < 8; ++k) {
            int e = e0 + k * 256;
            if (e < E) {
                int d = load_idx(edge, E + e, is64);
                atomicAdd(&lh[d >> 8], 1);
            }
        }
        __syncthreads();
        int* gh = hist + (size_t)blockIdx.x * B1N;
        for (int b = t; b < B1N; b += 256) gh[b] = lh[b];
    } else {
        const int tt = (blockIdx.x - nblkA) * 256 + t;
        if (tt >= NN * 32) return;
        const int n = tt >> 5;
        const int c = tt & 31;
        if (c >= 25) { xb[tt] = 0; return; }
        float2 v = *(const float2*)&x[n * 50 + 2 * c];
        xb[tt] = key16(v.x) | (key16(v.y) << 16);
    }
}

// One block per bin: exclusive scan of hist[b][bin] over blocks b (in place),
// bin total to binTotal[bin]. Supports nblk <= 1024 (4 per thread).
__global__ __launch_bounds__(256) void scanA_kernel(int* __restrict__ hist,
                                                    int nblk,
                                                    int* __restrict__ binTotal) {
    __shared__ int ts[256];
    const int bin = blockIdx.x;
    const int t = threadIdx.x;
    const int base = t * 4;
    int v0 = (base + 0 < nblk) ? hist[(size_t)(base + 0) * B1N + bin] : 0;
    int v1 = (base + 1 < nblk) ? hist[(size_t)(base + 1) * B1N + bin] : 0;
    int v2 = (base + 2 < nblk) ? hist[(size_t)(base + 2) * B1N + bin] : 0;
    int v3 = (base + 3 < nblk) ? hist[(size_t)(base + 3) * B1N + bin] : 0;
    const int s = v0 + v1 + v2 + v3;
    ts[t] = s;
    __syncthreads();
    for (int off = 1; off < 256; off <<= 1) {
        int u = (t >= off) ? ts[t - off] : 0;
        __syncthreads();
        ts[t] += u;
        __syncthreads();
    }
    int e = ts[t] - s;
    if (base + 0 < nblk) { hist[(size_t)(base + 0) * B1N + bin] = e; e += v0; }
    if (base + 1 < nblk) { hist[(size_t)(base + 1) * B1N + bin] = e; e += v1; }
    if (base + 2 < nblk) { hist[(size_t)(base + 2) * B1N + bin] = e; e += v2; }
    if (base + 3 < nblk) { hist[(size_t)(base + 3) * B1N + bin] = e; e += v3; }
    if (t == 255) binTotal[bin] = ts[255];
}

// In-block exclusive scan of binTotal[B1N] -> lbase[B1N+1] (LDS).
__device__ __forceinline__ void scan_bins_lds(const int* __restrict__ binTotal,
                                              int* ts, int* lbase) {
    const int t = threadIdx.x;
    const int base = t * 2;
    const int v0 = (base + 0 < B1N) ? binTotal[base + 0] : 0;
    const int v1 = (base + 1 < B1N) ? binTotal[base + 1] : 0;
    const int s = v0 + v1;
    ts[t] = s;
    __syncthreads();
    for (int off = 1; off < 256; off <<= 1) {
        int u = (t >= off) ? ts[t - off] : 0;
        __syncthreads();
        ts[t] += u;
        __syncthreads();
    }
    const int e = ts[t] - s;
    if (base + 0 < B1N) lbase[base + 0] = e;
    if (base + 1 < B1N) lbase[base + 1] = e + v0;
    if (t == 255) lbase[B1N] = ts[255];     // == E
    __syncthreads();
}

__global__ __launch_bounds__(256) void scatter_kernel(const void* edge, int E,
                                                      const int* __restrict__ hist,
                                                      const int* __restrict__ binTotal,
                                                      uint32* __restrict__ bucketed) {
    __shared__ int ts[256];
    __shared__ int lbase[B1N + 1];
    __shared__ int cur[B1N];
    const int is64 = edge_is64(edge);
    const int t = threadIdx.x;
    scan_bins_lds(binTotal, ts, lbase);
    const int* gh = hist + (size_t)blockIdx.x * B1N;
    for (int b = t; b < B1N; b += 256) cur[b] = lbase[b] + gh[b];
    __syncthreads();
    const int e0 = blockIdx.x * EPB_A + t;
#pragma unroll
    for (int k = 0; k < 8; ++k) {
        int e = e0 + k * 256;
        if (e < E) {
            int s = load_idx(edge, e, is64);
            int d = load_idx(edge, E + e, is64);
            int pos = atomicAdd(&cur[d >> 8], 1);   // LDS atomic
            bucketed[pos] = (uint32)s | ((uint32)(d & 255) << 17);
        }
    }
}

__global__ __launch_bounds__(256) void bucket_kernel(const uint32* __restrict__ bucketed,
                                                     const int* __restrict__ binTotal,
                                                     int* __restrict__ offsets,
                                                     int* __restrict__ csr_src) {
    __shared__ int ts[256];
    __shared__ int lbase[B1N + 1];
    __shared__ int h[256];
    __shared__ int sc[256];
    __shared__ int cur[256];
    const int bkt = blockIdx.x;
    const int t = threadIdx.x;
    scan_bins_lds(binTotal, ts, lbase);
    const int start = lbase[bkt];
    const int end   = lbase[bkt + 1];
    h[t] = 0;
    __syncthreads();
    for (int i = start + t; i < end; i += 256)
        atomicAdd(&h[bucketed[i] >> 17], 1);        // LDS atomic
    __syncthreads();
    const int v = h[t];
    sc[t] = v;
    __syncthreads();
    for (int off = 1; off < 256; off <<= 1) {
        int u = (t >= off) ? sc[t - off] : 0;
        __syncthreads();
        sc[t] += u;
        __syncthreads();
    }
    const int excl = sc[t] - v;
    const int node = bkt * 256 + t;
    if (node < NN) offsets[node] = start + excl;    // coalesced
    cur[t] = start + excl;
    __syncthreads();
    for (int i = start + t; i < end; i += 256) {
        uint32 p = bucketed[i];
        int pos = atomicAdd(&cur[p >> 17], 1);      // LDS atomic
        csr_src[pos] = (int)(p & 0x1FFFFu);         // L2-local scatter (16KB window)
    }
    if (bkt == B1N - 1 && t == 0) offsets[NN] = end;   // == E
}

// ---------------------------------------------------------------------------
// Gather-max kernels, key space. R23: TWO nodes per wave, software-pipelined
// (both index-window loads issue before any row round). R21 permuted window
// layout keeps shfl sources inside the executing sub-group.

__device__ __forceinline__ void g50_window(uint32* a_, int sidx, int mm,
                                           const char* hbase, uint32 joff,
                                           int p, int lb) {
    int k = p;
    for (; k + 14 < mm; k += 16) {
        const int kh = lb + (k >> 1);
#pragma unroll
        for (int kk = 0; kk < 8; ++kk) {
            int s = __shfl(sidx, kh + kk);     // intra-half source (R21 layout)
            uint32 u = *(const uint32*)(hbase + ((((uint32)s) << 7) | joff));
            a_[kk] = pkmax(a_[kk], u);
        }
    }
    for (; k + 6 < mm; k += 8) {
        const int kh = lb + (k >> 1);
#pragma unroll
        for (int kk = 0; kk < 4; ++kk) {
            int s = __shfl(sidx, kh + kk);
            uint32 u = *(const uint32*)(hbase + ((((uint32)s) << 7) | joff));
            a_[kk] = pkmax(a_[kk], u);
        }
    }
    for (; k < mm; k += 2) {
        int s = __shfl(sidx, lb + (k >> 1));
        uint32 u = *(const uint32*)(hbase + ((((uint32)s) << 7) | joff));
        a_[0] = pkmax(a_[0], u);
    }
}

__global__ void gather50_kernel(const uint32* __restrict__ hb,
                                const int* __restrict__ offsets,
                                const int* __restrict__ csr_src,
                                uint32* __restrict__ aggB) {
    const int tid  = threadIdx.x;
    const int g    = tid >> 6;
    const int lane = tid & 63;
    const int p    = lane >> 5;        // half-wave: edge parity
    const int j    = lane & 31;        // uint chunk
    const int n0   = (blockIdx.x * NPB + g) * 2;
    if (n0 >= NN) return;
    const int n1   = n0 + 1;
    const bool has1 = (n1 < NN);

    const int beg0 = offsets[n0];
    const int end0 = offsets[n0 + 1];
    const int beg1 = end0;                         // offsets[n1] == offsets[n0+1]
    const int end1 = has1 ? offsets[n1 + 1] : end0;
    const char* hbase = (const char*)hb;
    const uint32 joff = (uint32)(j << 2);
    const int lb = p << 5;             // this half's lane base
    const int myidx = 2 * j + p;       // R21 permuted window layout

    uint32 a_[8], b_[8];
#pragma unroll
    for (int k = 0; k < 8; ++k) { a_[k] = 0; b_[k] = 0; }

    // First windows of both nodes: issue BOTH index loads before any rows.
    const int d0 = end0 - beg0, d1 = end1 - beg1;
    const int mm0 = d0 < 64 ? d0 : 64;
    const int mm1 = d1 < 64 ? d1 : 64;
    int sidx0 = 0, sidx1 = 0;
    if (myidx < mm0) sidx0 = csr_src[beg0 + myidx];
    if (myidx < mm1) sidx1 = csr_src[beg1 + myidx];
    g50_window(a_, sidx0, mm0, hbase, joff, p, lb);
    g50_window(b_, sidx1, mm1, hbase, joff, p, lb);
    // Rare extra windows (degree > 64)
    for (int ib = beg0 + 64; ib < end0; ib += 64) {
        const int rem = end0 - ib;
        const int mm = rem < 64 ? rem : 64;
        int s = (myidx < mm) ? csr_src[ib + myidx] : 0;
        g50_window(a_, s, mm, hbase, joff, p, lb);
    }
    for (int ib = beg1 + 64; ib < end1; ib += 64) {
        const int rem = end1 - ib;
        const int mm = rem < 64 ? rem : 64;
        int s = (myidx < mm) ? csr_src[ib + myidx] : 0;
        g50_window(b_, s, mm, hbase, joff, p, lb);
    }

#pragma unroll
    for (int off2 = 4; off2 > 0; off2 >>= 1)
#pragma unroll
        for (int k = 0; k < off2; ++k) {
            a_[k] = pkmax(a_[k], a_[k + off2]);
            b_[k] = pkmax(b_[k], b_[k + off2]);
        }
    uint32 r0 = a_[0], r1 = b_[0];
    r0 = pkmax(r0, (uint32)__shfl_xor((int)r0, 32));   // combine parity halves
    r1 = pkmax(r1, (uint32)__shfl_xor((int)r1, 32));
    if (p == 0 && j < 25) {
        aggB[(size_t)n0 * 32 + j] = (beg0 == end0) ? 0x80008000u : r0;
        if (has1)
            aggB[(size_t)n1 * 32 + j] = (beg1 == end1) ? 0x80008000u : r1;
    }
}

__device__ __forceinline__ void g32_window(uint32* a_, int sidx, int mm,
                                           const char* hbase, uint32 coff,
                                           int e, int lb) {
    int k = e;
    for (; k + 12 < mm; k += 16) {
        const int m = lb + (k >> 2);
        int s0 = __shfl(sidx, m);              // intra-quarter sources
        int s1 = __shfl(sidx, m + 1);
        int s2 = __shfl(sidx, m + 2);
        int s3 = __shfl(sidx, m + 3);
        uint32 u0 = *(const uint32*)(hbase + ((((uint32)s0) << 6) | coff));
        uint32 u1 = *(const uint32*)(hbase + ((((uint32)s1) << 6) | coff));
        uint32 u2 = *(const uint32*)(hbase + ((((uint32)s2) << 6) | coff));
        uint32 u3 = *(const uint32*)(hbase + ((((uint32)s3) << 6) | coff));
        a_[0] = pkmax(a_[0], u0); a_[1] = pkmax(a_[1], u1);
        a_[2] = pkmax(a_[2], u2); a_[3] = pkmax(a_[3], u3);
    }
    for (; k < mm; k += 4) {
        int s = __shfl(sidx, lb + (k >> 2));
        uint32 u = *(const uint32*)(hbase + ((((uint32)s) << 6) | coff));
        a_[0] = pkmax(a_[0], u);
    }
}

__global__ void gather32_kernel(const uint32* __restrict__ hb,
                                const int* __restrict__ offsets,
                                const int* __restrict__ csr_src,
                                uint32* __restrict__ aggB) {
    const int tid  = threadIdx.x;
    const int g    = tid >> 6;
    const int lane = tid & 63;
    const int e    = lane >> 4;        // quarter-wave: edge slot mod 4
    const int c    = lane & 15;        // uint chunk
    const int n0   = (blockIdx.x * NPB + g) * 2;
    if (n0 >= NN) return;
    const int n1   = n0 + 1;
    const bool has1 = (n1 < NN);

    const int beg0 = offsets[n0];
    const int end0 = offsets[n0 + 1];
    const int beg1 = end0;                         // offsets[n1] == offsets[n0+1]
    const int end1 = has1 ? offsets[n1 + 1] : end0;
    const char* hbase = (const char*)hb;
    const uint32 coff = (uint32)(c << 2);
    const int lb = e << 4;             // this quarter's lane base
    const int myidx = 4 * c + e;       // R21 permuted window layout

    uint32 a_[4] = {0, 0, 0, 0};
    uint32 b_[4] = {0, 0, 0, 0};

    const int d0 = end0 - beg0, d1 = end1 - beg1;
    const int mm0 = d0 < 64 ? d0 : 64;
    const int mm1 = d1 < 64 ? d1 : 64;
    int sidx0 = 0, sidx1 = 0;
    if (myidx < mm0) sidx0 = csr_src[beg0 + myidx];
    if (myidx < mm1) sidx1 = csr_src[beg1 + myidx];
    g32_window(a_, sidx0, mm0, hbase, coff, e, lb);
    g32_window(b_, sidx1, mm1, hbase, coff, e, lb);
    for (int ib = beg0 + 64; ib < end0; ib += 64) {
        const int rem = end0 - ib;
        const int mm = rem < 64 ? rem : 64;
        int s = (myidx < mm) ? csr_src[ib + myidx] : 0;
        g32_window(a_, s, mm, hbase, coff, e, lb);
    }
    for (int ib = beg1 + 64; ib < end1; ib += 64) {
        const int rem = end1 - ib;
        const int mm = rem < 64 ? rem : 64;
        int s = (myidx < mm) ? csr_src[ib + myidx] : 0;
        g32_window(b_, s, mm, hbase, coff, e, lb);
    }

    uint32 r0 = pkmax(pkmax(a_[0], a_[1]), pkmax(a_[2], a_[3]));
    uint32 r1 = pkmax(pkmax(b_[0], b_[1]), pkmax(b_[2], b_[3]));
    r0 = pkmax(r0, (uint32)__shfl_xor((int)r0, 16));   // combine edge slots
    r0 = pkmax(r0, (uint32)__shfl_xor((int)r0, 32));
    r1 = pkmax(r1, (uint32)__shfl_xor((int)r1, 16));
    r1 = pkmax(r1, (uint32)__shfl_xor((int)r1, 32));
    if (lane < 16) {
        aggB[(size_t)n0 * 16 + lane] = (beg0 == end0) ? 0x80008000u : r0;
        if (has1)
            aggB[(size_t)n1 * 16 + lane] = (beg1 == end1) ? 0x80008000u : r1;
    }
}

// ---------------------------------------------------------------------------
// Dense kernel (R11-proven): one lane per node; 32 fp32 accumulators; wave-
// uniform weight addresses scalarize to s_load. Inputs key-encoded (dec_pk
// on load); MODE 0 stores relu output as keys (relu >= 0 -> OR 0x80008000);
// MODE 2 = log_softmax -> fp32.
template <int DIN, int ASTR, int HSTR, int OSTR, int MODE>
__global__ void dense_kernel(const uint32* __restrict__ aggB,
                             const uint32* __restrict__ hB,
                             const float* __restrict__ Wl,
                             const float* __restrict__ bl,
                             const float* __restrict__ Wr,
                             void* __restrict__ out_v) {
    const int n = blockIdx.x * blockDim.x + threadIdx.x;
    if (n >= NN) return;

    float acc[CD];
#pragma unroll
    for (int j = 0; j < CD; ++j) acc[j] = bl[j];

    {
        const uint32* row = aggB + (size_t)n * ASTR;
        for (int c = 0; c < DIN / 4; ++c) {
            uint2 u = *(const uint2*)&row[c * 2];
            u.x = dec_pk(u.x); u.y = dec_pk(u.y);
            float d0 = b2f_lo(u.x), d1 = b2f_hi(u.x);
            float d2 = b2f_lo(u.y), d3 = b2f_hi(u.y);
            const float* w = Wl + c * 4 * CD;
#pragma unroll
            for (int j = 0; j < CD; ++j)
                acc[j] += d0 * w[j] + d1 * w[CD + j] + d2 * w[2 * CD + j] + d3 * w[3 * CD + j];
        }
        if (DIN % 4) {
            uint32 u = dec_pk(row[(DIN / 4) * 2]);
            float d0 = b2f_lo(u), d1 = b2f_hi(u);
            const float* w = Wl + (DIN - 2) * CD;
#pragma unroll
            for (int j = 0; j < CD; ++j)
                acc[j] += d0 * w[j] + d1 * w[CD + j];
        }
    }
    {
        const uint32* row = hB + (size_t)n * HSTR;
        for (int c = 0; c < DIN / 4; ++c) {
            uint2 u = *(const uint2*)&row[c * 2];
            u.x = dec_pk(u.x); u.y = dec_pk(u.y);
            float d0 = b2f_lo(u.x), d1 = b2f_hi(u.x);
            float d2 = b2f_lo(u.y), d3 = b2f_hi(u.y);
            const float* w = Wr + c * 4 * CD;
#pragma unroll
            for (int j = 0; j < CD; ++j)
                acc[j] += d0 * w[j] + d1 * w[CD + j] + d2 * w[2 * CD + j] + d3 * w[3 * CD + j];
        }
        if (DIN % 4) {
            uint32 u = dec_pk(row[(DIN / 4) * 2]);
            float d0 = b2f_lo(u), d1 = b2f_hi(u);
            const float* w = Wr + (DIN - 2) * CD;
#pragma unroll
            for (int j = 0; j < CD; ++j)
                acc[j] += d0 * w[j] + d1 * w[CD + j];
        }
    }

    if (MODE == 0) {
        uint32* orow = (uint32*)out_v + (size_t)n * OSTR;
#pragma unroll
        for (int c = 0; c < CD / 2; ++c) {
            float a0 = fmaxf(acc[2 * c],     0.0f);
            float a1 = fmaxf(acc[2 * c + 1], 0.0f);
            // relu output >= 0 -> key encode is just setting the top bit
            orow[c] = ((uint32)f2b(a0) | ((uint32)f2b(a1) << 16)) | 0x80008000u;
        }
    } else {
        float m = acc[0];
#pragma unroll
        for (int j = 1; j < CD; ++j) m = fmaxf(m, acc[j]);
        float s = 0.0f;
#pragma unroll
        for (int j = 0; j < CD; ++j) s += expf(acc[j] - m);
        const float lse = m + logf(s);
        float* orow = (float*)out_v + (size_t)n * CD;
#pragma unroll
        for (int j = 0; j < CD; ++j) orow[j] = acc[j] - lse;
    }
}

// ---------------------------------------------------------------------------
extern "C" void kernel_launch(void* const* d_in, const int* in_sizes, int n_in,
                              void* d_out, int out_size, void* d_ws, size_t ws_size,
                              hipStream_t stream) {
    const float* x    = (const float*)d_in[0];
    const void*  edge = d_in[1];
    const float* Wl1 = (const float*)d_in[2];
    const float* bl1 = (const float*)d_in[3];
    const float* Wr1 = (const float*)d_in[4];
    const float* Wl2 = (const float*)d_in[5];
    const float* bl2 = (const float*)d_in[6];
    const float* Wr2 = (const float*)d_in[7];
    const float* Wl3 = (const float*)d_in[8];
    const float* bl3 = (const float*)d_in[9];
    const float* Wr3 = (const float*)d_in[10];

    const int E = in_sizes[1] / 2;

    // Workspace carve-up (256B aligned), ~26 MB. bucketed + hist live in
    // d_out (dead before agg1 is written there); h2b reuses xb (dead after
    // dense-L1); agg3 reuses h1b (dead after dense-L2).
    char* ws = (char*)d_ws;
    size_t off = 0;
    auto carve = [&](size_t bytes) {
        void* p = ws + off;
        off = (off + bytes + 255) & ~(size_t)255;
        return p;
    };
    int*    offsets   = (int*)   carve((size_t)(NN + 1) * 4);
    int*    binTotal  = (int*)   carve((size_t)B1N * 4);
    int*    csr_src   = (int*)   carve((size_t)E * 4);
    uint32* xb        = (uint32*)carve((size_t)NN * 32 * 4);  // 12.8 MB
    uint32* h1b       = (uint32*)carve((size_t)NN * 16 * 4);  // 6.4 MB
    (void)ws_size; (void)n_in; (void)out_size;

    uint32* bucketed = (uint32*)d_out;     // 6.4 MB, dead before agg1
    int*    hist     = (int*)((char*)d_out + (((size_t)E * 4 + 255) & ~(size_t)255));
    uint32* agg1 = (uint32*)d_out;         // L1 agg, stride 32 (12.8 MB = d_out)
    uint32* agg2 = (uint32*)d_out;         // L2 agg, stride 16
    uint32* h2b  = xb;                     // xb dead after dense-L1
    uint32* agg3 = h1b;                    // h1b dead after dense-L2

    // CSR build, LDS-atomic bucketing; cvt fused into the hist dispatch.
    const int nblkA = (E + EPB_A - 1) / EPB_A;     // 782 for E=1.6M
    const int cvtb  = (NN * 32 + 255) / 256;       // 12500
    cvt_hist_kernel<<<nblkA + cvtb, 256, 0, stream>>>(x, xb, edge, E, hist, nblkA);
    scanA_kernel<<<B1N, 256, 0, stream>>>(hist, nblkA, binTotal);
    scatter_kernel<<<nblkA, 256, 0, stream>>>(edge, E, hist, binTotal, bucketed);
    bucket_kernel<<<B1N, 256, 0, stream>>>(bucketed, binTotal, offsets, csr_src);

    const int gb = (NN + NPB * 2 - 1) / (NPB * 2);   // 2 nodes per wave
    const int db = (NN + 255) / 256;                 // lane per node

    // Layer 1: 50 -> 32, relu
    gather50_kernel<<<gb, 256, 0, stream>>>(xb, offsets, csr_src, agg1);
    dense_kernel<50, 32, 32, 16, 0><<<db, 256, 0, stream>>>(agg1, xb, Wl1, bl1, Wr1, h1b);
    // Layer 2: 32 -> 32, relu
    gather32_kernel<<<gb, 256, 0, stream>>>(h1b, offsets, csr_src, agg2);
    dense_kernel<32, 16, 16, 16, 0><<<db, 256, 0, stream>>>(agg2, h1b, Wl2, bl2, Wr2, h2b);
    // Layer 3: 32 -> 32, log_softmax -> fp32 d_out
    gather32_kernel<<<gb, 256, 0, stream>>>(h2b, offsets, csr_src, agg3);
    dense_kernel<32, 16, 16, 0, 2><<<db, 256, 0, stream>>>(agg3, h2b, Wl3, bl3, Wr3, d_out);
}